// Round 2
// baseline (357.573 us; speedup 1.0000x reference)
//
#include <hip/hip_runtime.h>
#include <stdint.h>

// CostVolume: out[b, d=(dy+4)*9+(dx+4), h, w] =
//   leaky_relu( mean_c( x1[b,c,h,w] * x2[b,c,h+dy,w+dx] ), 0.1 ), zero-padded x2.
//
// bf16 MFMA 16x16x32 along w: M = x1 w-positions (16), N = staged x2 columns,
// K = channels. Each wave owns one (h-row, M-tile); 9 dy x 2 N-tiles = 18 MFMA
// per k-chunk; the 9 dx diagonals are extracted in the epilogue and transposed
// through LDS for coalesced w-contiguous stores.
//
// Block = 512 threads (8 waves), TH=4 h-rows x WT=32 w-cols. LDS 38.4 KB ->
// 2 blocks/CU so staging of one block overlaps MFMA of the other.

#define CCH   128
#define HH    96
#define WW    320
#define HWs   (HH * WW)      // 30720
#define CHWs  (CCH * HWs)
#define ND    81

#define TH 4    // output h rows per block
#define WT 32   // output w cols per block (2 M-tiles of 16)
#define SW 40   // staged x2 cols: W0-4 .. W0+35
#define SR 12   // staged x2 rows: h0-4 .. h0+7
#define KC 32   // channels per chunk (one MFMA K-step)
#define KP 40   // padded k-stride in shorts: 80B rows -> 16B aligned, 2-way banks (free)
#define OP 132  // obuf d-slice stride in floats (128 + 4: de-conflicts band scatter)

typedef __attribute__((ext_vector_type(8))) short        short8;
typedef __attribute__((ext_vector_type(4))) float        floatx4;
typedef __attribute__((ext_vector_type(4))) unsigned int uint4v;

// round-to-nearest-even fp32 -> bf16 (no NaN handling needed: inputs are normals)
__device__ __forceinline__ unsigned int bf16rne(float f) {
  unsigned int u = __float_as_uint(f);
  return (u + 0x7fffu + ((u >> 16) & 1u)) >> 16;
}
__device__ __forceinline__ unsigned int pk2(float lo, float hi) {
  return bf16rne(lo) | (bf16rne(hi) << 16);
}

__global__ __launch_bounds__(512, 4) void cost_volume_kernel(
    const float* __restrict__ x1g, const float* __restrict__ x2g,
    float* __restrict__ out)
{
  extern __shared__ char smem[];
  short* x2s  = (short*)smem;       // SR*SW*KP shorts = 38400 B
  float* obuf = (float*)smem;       // aliases x2s after k-loop; 45*OP*4 = 23760 B

  const int b  = blockIdx.x & 7;    // batch spread across XCDs for L2 locality
  const int g  = blockIdx.x >> 3;
  const int hs = g % 24;
  const int ws = g / 24;
  const int h0 = hs * TH;
  const int W0 = ws * WT;

  const int t    = threadIdx.x;
  const int wave = t >> 6;
  const int lane = t & 63;
  const int hl   = wave >> 1;   // 0..3: h row owned by this wave
  const int mt   = wave & 1;    // 0..1: M-tile owned by this wave
  const int q    = lane >> 4;   // quad
  const int ln   = lane & 15;

  const float* x1b = x1g + (size_t)b * CHWs;
  const float* x2b = x2g + (size_t)b * CHWs;

  // --- staging decode: x2 has SR*SW*(KC/8) = 1920 octet-units, 512 threads ---
  int x2_go[4], x2_lo[4];
#pragma unroll
  for (int s = 0; s < 4; ++s) {
    int u = t + s * 512;
    if (u < SR * SW * 4) {
      int j  = u % SW;
      int ro = u / SW;
      int o  = ro & 3;            // which 8-channel octet
      int r  = ro >> 2;           // staged row
      int gr = h0 - 4 + r;
      int gc = W0 - 4 + j;
      x2_lo[s] = (r * SW + j) * KP + o * 8;
      x2_go[s] = (gr >= 0 && gr < HH && gc >= 0 && gc < WW)
                   ? (o * 8 * HWs + gr * WW + gc) : -1;
    } else { x2_lo[s] = -1; x2_go[s] = -1; }
  }
  // x1 A-frag: direct from global (no halo, each element read once)
  const int x1off = (h0 + hl) * WW + W0 + mt * 16 + ln;

  floatx4 acc[9][2] = {};   // 72 VGPRs, persist across k-chunks

  for (int kc = 0; kc < CCH / KC; ++kc) {
    const int cbase = kc * KC * HWs;

    // ---- x1 A-frag loads (independent of LDS; overlap the barrier) ----
    const float* p1 = x1b + cbase + (size_t)q * 8 * HWs + x1off;
    float a0 = p1[0 * HWs], a1 = p1[1 * HWs], a2 = p1[2 * HWs], a3 = p1[3 * HWs];
    float a4 = p1[4 * HWs], a5 = p1[5 * HWs], a6 = p1[6 * HWs], a7 = p1[7 * HWs];

    // ---- stage x2 chunk (fp32 -> bf16 RNE, zero-pad OOB) ----
#pragma unroll
    for (int s = 0; s < 4; ++s) {
      if (x2_lo[s] >= 0) {
        unsigned int p01 = 0, p23 = 0, p45 = 0, p67 = 0;
        if (x2_go[s] >= 0) {
          const float* p = x2b + cbase + x2_go[s];
          float f0 = p[0 * HWs], f1 = p[1 * HWs], f2 = p[2 * HWs], f3 = p[3 * HWs];
          float f4 = p[4 * HWs], f5 = p[5 * HWs], f6 = p[6 * HWs], f7 = p[7 * HWs];
          p01 = pk2(f0, f1); p23 = pk2(f2, f3);
          p45 = pk2(f4, f5); p67 = pk2(f6, f7);
        }
        *(uint4v*)&x2s[x2_lo[s]] = (uint4v){p01, p23, p45, p67};
      }
    }

    short8 af;
    {
      uint4v av = (uint4v){pk2(a0, a1), pk2(a2, a3), pk2(a4, a5), pk2(a6, a7)};
      af = *(short8*)&av;
    }
    __syncthreads();

    // ---- MFMA: wave(hl,mt) does 9 dy x 2 N-tiles ----
#pragma unroll
    for (int dyi = 0; dyi < 9; ++dyi) {
      const int r = hl + dyi;                 // staged row = h + dy (shifted +4)
#pragma unroll
      for (int jn = 0; jn < 2; ++jn) {
        int jc = (mt + jn) * 16 + ln;
        if (jc > SW - 1) jc = SW - 1;         // clamped lanes are never extracted
        const short8 bf = *(const short8*)&x2s[(r * SW + jc) * KP + q * 8];
        acc[dyi][jn] = __builtin_amdgcn_mfma_f32_16x16x32_bf16(af, bf, acc[dyi][jn], 0, 0, 0);
      }
    }
    __syncthreads();
  }

  // ---- epilogue: extract diagonal band dx+4 = jn*16 + n - m, two d-phases ----
  const size_t obase = (size_t)b * (ND * (size_t)HWs);
#pragma unroll
  for (int ph = 0; ph < 2; ++ph) {
    const int d0 = ph ? 5 : 0, d1 = ph ? 9 : 5;     // dyi range
#pragma unroll
    for (int dyi = 0; dyi < 9; ++dyi) {
      if (dyi < d0 || dyi >= d1) continue;
#pragma unroll
      for (int jn = 0; jn < 2; ++jn)
#pragma unroll
        for (int reg = 0; reg < 4; ++reg) {
          const int m   = q * 4 + reg;
          const int dxi = jn * 16 + ln - m;
          if (dxi >= 0 && dxi < 9) {
            float v = acc[dyi][jn][reg] * (1.0f / 128.0f);
            v = (v < 0.0f) ? 0.1f * v : v;
            obuf[((dyi - d0) * 9 + dxi) * OP + hl * WT + mt * 16 + m] = v;
          }
        }
    }
    __syncthreads();
    const int nd   = (d1 - d0) * 9;           // 45 then 36 d-slices
    const int dbas = d0 * 9;
    for (int idx = t; idx < nd * TH * WT; idx += 512) {
      const int dl  = idx >> 7;               // /(TH*WT)=128
      const int rem = idx & 127;
      const int hh  = rem >> 5;
      const int wl  = rem & 31;
      out[obase + (size_t)(dbas + dl) * HWs + (h0 + hh) * WW + W0 + wl]
          = obuf[dl * OP + rem];
    }
    __syncthreads();
  }
}

extern "C" void kernel_launch(void* const* d_in, const int* in_sizes, int n_in,
                              void* d_out, int out_size, void* d_ws, size_t ws_size,
                              hipStream_t stream) {
  const float* x1 = (const float*)d_in[0];
  const float* x2 = (const float*)d_in[1];
  float* out = (float*)d_out;
  // grid: 8 batches x 24 h-strips x 10 w-tiles = 1920 blocks
  cost_volume_kernel<<<dim3(1920), dim3(512), 38400, stream>>>(x1, x2, out);
}